// Round 2
// baseline (49.914 us; speedup 1.0000x reference)
//
#include <hip/hip_runtime.h>
#include <math.h>

// NormalLoss: for each template vertex (M=6890), take the K=15 scan points
// (N=20000) with LARGEST distance, among them pick the min-angle normal
// match, loss = mean ||sv[sel]-tv||.
//
// Round-8 design: octant-partitioned radial sort.
//   Ledger: launch glue is small (round-7 fusion was neutral) -> knn
//   dominates (~20 us). Its direction-blind bound (smax+|tv|) forces every
//   vertex to scan all high-|p| shells. New: points bucketed by
//   (octant(sign pattern), |p| shell) -> 2048 buckets. Per (octant o,
//   64-chunk k) a radial upper bound r is tabulated; for vertex tv the
//   exact bound  max d^2 over octant suffix = r^2 + |tv|^2 + 2 r g_o,
//   g_o^2 = sum tv_i^2 over components where o's sign OPPOSES tv_i
//   (g=0 same-side octant). Vertex bootstraps its top-15 in the argmax-g
//   octant (thr near-final immediately); remaining 7 octants typically
//   break at their first chunk check.
//   Safety: top radial bucket (|p|^2 >= 31.875) gets r = +inf (removes
//   the old bucket-clamp unsafety); all bound-vs-thr compares keep the
//   *1.00001 safe-side margin; skips only drop points strictly < thr, so
//   the (d2 desc, idx asc) total-order top-K -- and hence the output --
//   is bit-identical to the exhaustive scan.
//   Pipeline: scatter (fused hist+scan+scatter, per-block prefix
//   re-histogram for write bases) -> knn (per-wave vertex, bitonic
//   bootstrap + sorted-insert machinery unchanged) -> 1-block reduce
//   (no atomics on out anywhere; all ws reads are of ws bytes written
//   this launch -> poison-safe).

constexpr int K = 15;
constexpr int RBUCK = 256;         // radial shells per octant (0.125-wide |p|^2)
constexpr int NBUCK2 = 8 * RBUCK;  // total buckets
constexpr int WAVES = 4;           // waves (=vertices) per block in main kernel

__device__ __forceinline__ int rbucket_of(float k2) {
    int b = (int)(k2 * 8.0f);
    b = b > (RBUCK - 1) ? (RBUCK - 1) : b;
    return (RBUCK - 1) - b;        // 0 = largest |p| shell
}
__device__ __forceinline__ int octant_of(float x, float y, float z) {
    return (x < 0.0f ? 1 : 0) | (y < 0.0f ? 2 : 0) | (z < 0.0f ? 4 : 0);
}

// Fused hist + scan + scatter over 2048 (octant,shell) buckets. Each block:
//   1) LDS-histograms points [0, base)  -> mine8 (write base per bucket)
//   2) LDS-histograms points [base, N)  -> h becomes bucket totals
//   3) scan over 2048 buckets (8/thread serial + Kogge-Stone over 256)
//   4) block 0 tabulates rmax[o][k] from shell edges + octStartG
//   5) scatters its own 256 points via LDS cursors
__global__ __launch_bounds__(256) void scatter_kernel(
    const float* __restrict__ sv,
    float4*      __restrict__ sorted,    // [N] out: (x,y,z,bitcast(origIdx))
    float*       __restrict__ rmax,      // [8*nb] out: radial bound per (oct,chunk)
    int*         __restrict__ octStartG, // [9] out: octant start positions (+N)
    int N, int nb)
{
    __shared__ int h[NBUCK2];
    __shared__ int startSh[NBUCK2];
    __shared__ int cursor[NBUCK2];
    const int t    = threadIdx.x;
    const int base = blockIdx.x * 256;

#pragma unroll 8
    for (int j = t; j < NBUCK2; j += 256) h[j] = 0;
    __syncthreads();

    // --- prefix histogram: points [0, base) ---
    for (int i = t; i < base; i += 256) {
        float x = sv[3*i], y = sv[3*i+1], z = sv[3*i+2];
        int b = (octant_of(x, y, z) << 8) |
                rbucket_of(fmaf(x, x, fmaf(y, y, z*z)));
        atomicAdd(&h[b], 1);
    }
    __syncthreads();
    int mine8[8];
#pragma unroll
    for (int j = 0; j < 8; ++j) mine8[j] = h[t*8 + j];
    __syncthreads();

    // --- own point (kept in registers for the scatter at the end) ---
    float px = 0.0f, py = 0.0f, pz = 0.0f;
    int pb = 0;
    const bool has = (base + t) < N;
    if (has) {
        px = sv[3*(base+t)]; py = sv[3*(base+t)+1]; pz = sv[3*(base+t)+2];
        pb = (octant_of(px, py, pz) << 8) |
             rbucket_of(fmaf(px, px, fmaf(py, py, pz*pz)));
        atomicAdd(&h[pb], 1);
    }
    // --- rest of the suffix: [base+256, N) ---
    for (int i = base + 256 + t; i < N; i += 256) {
        float x = sv[3*i], y = sv[3*i+1], z = sv[3*i+2];
        int b = (octant_of(x, y, z) << 8) |
                rbucket_of(fmaf(x, x, fmaf(y, y, z*z)));
        atomicAdd(&h[b], 1);
    }
    __syncthreads();

    // --- exclusive scan over 2048 buckets ---
    int tot8[8]; int tot = 0;
#pragma unroll
    for (int j = 0; j < 8; ++j) { tot8[j] = h[t*8 + j]; tot += tot8[j]; }
    cursor[t] = tot;                       // reuse cursor[0..255] as sums
    __syncthreads();
    for (int d = 1; d < 256; d <<= 1) {
        int u = (t >= d) ? cursor[t - d] : 0;
        __syncthreads();
        cursor[t] += u;
        __syncthreads();
    }
    int running = cursor[t] - tot;         // exclusive over thread groups
    __syncthreads();                       // KS reads done before overwrite
#pragma unroll
    for (int j = 0; j < 8; ++j) {
        startSh[t*8 + j] = running;
        cursor[t*8 + j]  = running + mine8[j];   // this block's write base
        running += tot8[j];
    }
    __syncthreads();

    if (blockIdx.x == 0) {
        if (t < 8) octStartG[t] = startSh[t << 8];
        if (t == 8) octStartG[8] = N;
        // rmax[o][k]: radial |p| upper bound for octant-o positions >= oS+64k.
        // Shell at that position found by binary search over startSh; bound =
        // upper edge of that shell. Top shell (rb==0, |p|^2 may exceed the
        // clamp) -> +inf (never breaks there; exact-safe).
        for (int o = 0; o < 8; ++o) {
            int oS = startSh[o << 8];
            int oE = (o < 7) ? startSh[(o + 1) << 8] : N;
            for (int k = t; oS + (k << 6) < oE; k += 256) {
                int pos = oS + (k << 6);
                int lo = 0, hi = RBUCK - 1;
                while (lo < hi) {
                    int mid = (lo + hi + 1) >> 1;
                    if (startSh[(o << 8) + mid] <= pos) lo = mid; else hi = mid - 1;
                }
                rmax[o*nb + k] = (lo == 0) ? 3.0e38f
                                           : sqrtf((float)(RBUCK - lo) * 0.125f);
            }
        }
    }

    if (has) {
        int pos = atomicAdd(&cursor[pb], 1);   // LDS atomic
        sorted[pos] = make_float4(px, py, pz, __int_as_float(base + t));
    }
}

template<bool SORTED>
__global__ __launch_bounds__(WAVES * 64) void knn_loss_kernel(
    const float4* __restrict__ pts,    // octant/radial-sorted points (SORTED)
    const float*  __restrict__ rmax,   // [8*nbo] radial bound per (oct,chunk)
    const int*    __restrict__ octStartG, // [9]
    const float*  __restrict__ sv,     // [N,3] original scan vertices
    const float*  __restrict__ tv,     // [M,3]
    const float*  __restrict__ sn,     // [N,3]
    const float*  __restrict__ tn,     // [M,3]
    float* __restrict__ partial,       // [gridDim.x] per-block sums
    int N, int M, float invM, int nbo)
{
    __shared__ float bsum[WAVES];
    const int lane = threadIdx.x & 63;
    const int w    = threadIdx.x >> 6;
    const int m    = blockIdx.x * WAVES + w;
    const bool valid = (m < M);

    float contrib = 0.0f;
    if (valid) {
        const float tvx = tv[3*m], tvy = tv[3*m+1], tvz = tv[3*m+2];
        const float tx2 = tvx*tvx, ty2 = tvy*tvy, tz2 = tvz*tvz;
        const float t2  = tx2 + ty2 + tz2;

        // per-octant opposition energy: contribution of component i to g^2
        // if octant sign is negative (cxn) / positive (cxp).
        const float cxn = (tvx > 0.0f) ? tx2 : 0.0f;
        const float cxp = (tvx < 0.0f) ? tx2 : 0.0f;
        const float cyn = (tvy > 0.0f) ? ty2 : 0.0f;
        const float cyp = (tvy < 0.0f) ? ty2 : 0.0f;
        const float czn = (tvz > 0.0f) ? tz2 : 0.0f;
        const float czp = (tvz < 0.0f) ? tz2 : 0.0f;
        auto g2v = [&](int o) {
            return ((o & 1) ? cxn : cxp) + ((o & 2) ? cyn : cyp)
                 + ((o & 4) ? czn : czp);
        };

        int ob = 0; float bg = 0.0f;
        int prefS = 0; float prefR0 = 0.0f;
        if (SORTED) {
            // most-opposed octant = argmax g^2
            bg = g2v(0);
#pragma unroll
            for (int o = 1; o < 8; ++o) {
                float g2o = g2v(o);
                if (g2o > bg) { bg = g2o; ob = o; }
            }
            // prefetch octant starts (9) and each octant's chunk-0 radial
            // bound into lanes; fetched once, redistributed via shfl.
            if (lane < 9) prefS = octStartG[lane];
            if (lane < 8) prefR0 = rmax[lane * nbo];
        }

        // ---- bootstrap: bitonic-sort 64 points desc by (d2, -idx) ----
        float v; int idx;
        int oS = 0, oE = N;
        {
            int l; bool hasB;
            float px, py, pz;
            if (SORTED) {
                oS = __shfl(prefS, ob); oE = __shfl(prefS, ob + 1);
                l = oS + lane; hasB = l < oE;
                float4 q = pts[hasB ? l : 0];
                px = q.x; py = q.y; pz = q.z; idx = __float_as_int(q.w);
            } else {
                l = lane; hasB = l < N;
                int g = hasB ? l : 0;
                px = sv[3*g]; py = sv[3*g+1]; pz = sv[3*g+2]; idx = l;
            }
            float dx = px - tvx, dy = py - tvy, dz = pz - tvz;
            v = fmaf(dx, dx, fmaf(dy, dy, dz * dz));
            if (!hasB) { v = -1.0f; idx = 0x7FFFFFFF; }
        }
#pragma unroll
        for (int k = 2; k <= 64; k <<= 1) {
#pragma unroll
            for (int j = k >> 1; j > 0; j >>= 1) {
                float ov = __shfl_xor(v, j);
                int   oi = __shfl_xor(idx, j);
                bool up    = ((lane & k) == 0);   // descending segment
                bool lower = ((lane & j) == 0);
                bool mine  = (v > ov) || (v == ov && idx < oi); // total order
                bool keep  = lower ? (up ? mine : !mine) : (up ? !mine : mine);
                if (!keep) { v = ov; idx = oi; }
            }
        }
        // lanes 0..K-1 hold the exact top-K of the bootstrap 64 (sorted desc)
        float eV = (lane < K) ? v : -1.0f;
        int   eI = idx;
        float thr = __shfl(v, K - 1);   // current 15th-largest d2

        // candidate machinery (shared by both paths), processes one 64-chunk
        auto process_chunk = [&](float d2, int oi2, bool has) {
            // >= : equal-d2 candidate with lower original idx must displace
            unsigned long long mb = __ballot(has && (d2 >= thr));
            while (mb) {
                int src = __ffsll(mb) - 1;
                mb &= mb - 1;
                float cv = __shfl(d2, src);
                int   ci = __shfl(oi2, src);
                unsigned long long bb =
                    __ballot((eV > cv) || (eV == cv && eI < ci)) & 0x7FFFull;
                int p = __popcll(bb);
                if (p < K) {   // wave-uniform
                    float uv = __shfl_up(eV, 1);
                    int   ui = __shfl_up(eI, 1);
                    if (lane < K) {
                        if (lane == p)      { eV = cv; eI = ci; }
                        else if (lane > p)  { eV = uv; eI = ui; }
                    }
                    thr = __shfl(eV, K - 1);
                    if (mb) mb &= __ballot(d2 >= thr);
                }
            }
        };

        if (SORTED) {
            // per-octant scan with exact directional bound
            auto scan_octant = [&](int o, int s, int e, int kStart,
                                   float r0, float g) {
                for (int k = kStart; ; ++k) {
                    int pos = s + (k << 6);
                    if (pos >= e) break;
                    float r  = (k == 0) ? r0 : rmax[o*nbo + k];
                    float b2 = fmaf(2.0f*g, r, fmaf(r, r, t2));
                    if (b2 * 1.00001f < thr) break;  // margin: fp-safe skip
                    int i = pos + lane; bool has = i < e;
                    float4 q = pts[has ? i : pos];
                    float dx = q.x - tvx, dy = q.y - tvy, dz = q.z - tvz;
                    float d2 = fmaf(dx, dx, fmaf(dy, dy, dz * dz));
                    process_chunk(d2, __float_as_int(q.w), has);
                }
            };
            // rest of bootstrap octant first (thr is already near-final)
            scan_octant(ob, oS, oE, 1, 0.0f, sqrtf(bg));
            for (int o2 = 0; o2 < 8; ++o2) {
                if (o2 == ob) continue;
                int s2 = __shfl(prefS, o2), e2 = __shfl(prefS, o2 + 1);
                scan_octant(o2, s2, e2, 0, __shfl(prefR0, o2), sqrtf(g2v(o2)));
            }
        } else {
            for (int ib = 64; ib < N; ib += 64) {
                int  i   = ib + lane;
                bool has = (i < N);
                int g = has ? i : 0;
                float dx = sv[3*g] - tvx, dy = sv[3*g+1] - tvy,
                      dz = sv[3*g+2] - tvz;
                float d2 = fmaf(dx, dx, fmaf(dy, dy, dz * dz));
                process_chunk(d2, i, has);
            }
        }

        // ---- epilogue: argmin angle, tie-break by top-k rank (= lane) ----
        const float tnx = tn[3*m], tny = tn[3*m+1], tnz = tn[3*m+2];
        float ang = 3.0e38f;
        int myI = eI;
        if (lane < K && myI != 0x7FFFFFFF) {
            float dot = sn[3*myI]*tnx + sn[3*myI+1]*tny + sn[3*myI+2]*tnz;
            dot = fminf(1.0f, fmaxf(-1.0f, dot));
            ang = acosf(dot) * 57.29577951308232f;   // degrees, matches jnp
        }
        float ba = ang; int br = lane; int bi = myI;
#pragma unroll
        for (int s = 1; s < 16; s <<= 1) {
            float oa  = __shfl_xor(ba, s);
            int   orr = __shfl_xor(br, s);
            int   oi  = __shfl_xor(bi, s);
            bool take = (oa < ba) || (oa == ba && orr < br);
            if (take) { ba = oa; br = orr; bi = oi; }
        }
        if (lane == 0) {
            float dx = sv[3*bi]   - tvx;
            float dy = sv[3*bi+1] - tvy;
            float dz = sv[3*bi+2] - tvz;
            contrib = sqrtf(dx*dx + dy*dy + dz*dz) * invM;
        }
    }

    if (lane == 0) bsum[w] = contrib;
    __syncthreads();
    if (threadIdx.x == 0)
        partial[blockIdx.x] = bsum[0] + bsum[1] + bsum[2] + bsum[3];
}

__global__ __launch_bounds__(256) void reduce_kernel(
    const float* __restrict__ partial, float* __restrict__ out, int n)
{
    __shared__ float sh[4];
    const int lane = threadIdx.x & 63;
    const int w    = threadIdx.x >> 6;
    float s = 0.0f;
    for (int i = threadIdx.x; i < n; i += 256) s += partial[i];
#pragma unroll
    for (int d = 1; d < 64; d <<= 1) s += __shfl_xor(s, d);
    if (lane == 0) sh[w] = s;
    __syncthreads();
    if (threadIdx.x == 0) out[0] = sh[0] + sh[1] + sh[2] + sh[3];
}

extern "C" void kernel_launch(void* const* d_in, const int* in_sizes, int n_in,
                              void* d_out, int out_size, void* d_ws, size_t ws_size,
                              hipStream_t stream) {
    const float* sv = (const float*)d_in[0];   // scan_vertices     [1,N,3]
    const float* tv = (const float*)d_in[1];   // template_vertices [1,M,3]
    const float* sn = (const float*)d_in[2];   // scan_normals      [N,3]
    const float* tn = (const float*)d_in[3];   // template_normals  [M,3]
    // d_in[4] = K_knn (fixed 15, compile-time)

    int N = in_sizes[0] / 3;
    int M = in_sizes[1] / 3;
    int nb = (N + 63) / 64;                    // max chunks per octant
    float* out = (float*)d_out;
    float invM = 1.0f / (float)M;
    int grid  = (M + WAVES - 1) / WAVES;
    int nblk  = (N + 255) / 256;

    // d_ws: [sorted float4 x N][rmax 8*nb][octStartG 9 ints][partial x grid]
    size_t offSorted  = 0;
    size_t offRmax    = offSorted + (size_t)N * sizeof(float4);
    size_t offOct     = (offRmax + (size_t)8 * nb * sizeof(float) + 15) & ~(size_t)15;
    size_t offPartial = (offOct + 9 * sizeof(int) + 15) & ~(size_t)15;
    size_t need       = offPartial + (size_t)grid * sizeof(float);

    if (ws_size >= need) {
        float4* sorted   = (float4*)((char*)d_ws + offSorted);
        float*  rmaxp    = (float*) ((char*)d_ws + offRmax);
        int*    octStart = (int*)   ((char*)d_ws + offOct);
        float*  partial  = (float*) ((char*)d_ws + offPartial);

        scatter_kernel<<<nblk, 256, 0, stream>>>(sv, sorted, rmaxp,
                                                 octStart, N, nb);
        knn_loss_kernel<true><<<grid, WAVES * 64, 0, stream>>>(
            sorted, rmaxp, octStart, sv, tv, sn, tn, partial, N, M, invM, nb);
        reduce_kernel<<<1, 256, 0, stream>>>(partial, out, grid);
    } else if (ws_size >= (size_t)grid * sizeof(float)) {
        float* partial = (float*)d_ws;
        knn_loss_kernel<false><<<grid, WAVES * 64, 0, stream>>>(
            nullptr, nullptr, nullptr, sv, tv, sn, tn, partial, N, M, invM, nb);
        reduce_kernel<<<1, 256, 0, stream>>>(partial, out, grid);
    }
}